// Round 1
// baseline (232.674 us; speedup 1.0000x reference)
//
#include <hip/hip_runtime.h>

// ---------------- problem constants ----------------
#define LL 2048
#define BB 16
#define HH 512
#define PP 256
#define MM (LL*BB)   // 32768 rows
#define NN 512       // all GEMMs: N=512
#define KK 512       // all GEMMs: K=512
#define NC 64        // scan chunks
#define CLEN 32      // chunk length (NC*CLEN == LL)

typedef __bf16 bf16x8 __attribute__((ext_vector_type(8)));
typedef float  f32x4  __attribute__((ext_vector_type(4)));

__device__ __forceinline__ unsigned short f2bf(float f) {
  unsigned u = __builtin_bit_cast(unsigned, f);
  u = (u + 0x7fffu + ((u >> 16) & 1u)) >> 16;   // RNE
  return (unsigned short)u;
}
__device__ __forceinline__ float bf2f(unsigned short s) {
  unsigned u = ((unsigned)s) << 16;
  return __builtin_bit_cast(float, u);
}

// ---------------- dtype detection for `d` (bool input; harness dtype ambiguous) ----
// Reads first 32KB (safe under all interpretations: int32->128KB, f32->128KB, u8->32KB).
// flag: 0 = int32 values {0,1}; 1 = float32 {0.0f,1.0f}; 2 = packed bytes {0,1}.
__global__ void detect_kernel(const unsigned int* __restrict__ dw, int* __restrict__ flag) {
  __shared__ int sInt, sFloat;
  if (threadIdx.x == 0) { sInt = 1; sFloat = 1; }
  __syncthreads();
  int allInt = 1, allFloat = 1;
  for (int i = threadIdx.x; i < 8192; i += 256) {
    unsigned v = dw[i];
    if (v > 1u) allInt = 0;
    if (v != 0u && v != 0x3f800000u) allFloat = 0;
  }
  if (!allInt) atomicAnd(&sInt, 0);
  if (!allFloat) atomicAnd(&sFloat, 0);
  __syncthreads();
  if (threadIdx.x == 0) *flag = sInt ? 0 : (sFloat ? 1 : 2);
}

__device__ __forceinline__ float keep_val(const void* d, int flag, int idx) {
  if (flag == 0) return 1.f - (float)((const int*)d)[idx];
  if (flag == 1) return 1.f - ((const float*)d)[idx];
  return 1.f - (float)((const unsigned char*)d)[idx];
}

// ---------------- weight precompute ----------------
// W1t[n][k] (512x512, bf16): n<256 -> Re(B_bar)[p=n][h=k]; n>=256 -> Im(B_bar)[p=n-256][h=k]
//   B_bar = ((Lam_bar-1)/Lam) * (B_re + i B_im)
// W2t[h][k] : k<256 -> 2*C_re[h][p=k]; k>=256 -> -2*C_im[h][p=k-256]
// W3t[n][k] = out2_w[k][n]
// lam_re/lam_im[p] = Lam_bar
__global__ void precompute_kernel(
    const float* __restrict__ Lre, const float* __restrict__ Lim,
    const float* __restrict__ Bre, const float* __restrict__ Bim,
    const float* __restrict__ Cre, const float* __restrict__ Cim,
    const float* __restrict__ lstep, const float* __restrict__ w2,
    unsigned short* __restrict__ W1t, unsigned short* __restrict__ W2t,
    unsigned short* __restrict__ W3t, float* __restrict__ lam_re,
    float* __restrict__ lam_im) {
  int t = blockIdx.x * 256 + threadIdx.x;   // 0..262143
  int k = t & (KK - 1);
  int n = t >> 9;
  {
    int p = n & (PP - 1);
    float lr = Lre[p], li = Lim[p];
    float st = expf(lstep[p]);
    float er = expf(lr * st);
    float ang = li * st;
    float lbr = er * cosf(ang), lbi = er * sinf(ang);
    float den = lr * lr + li * li;
    float wr = ((lbr - 1.f) * lr + lbi * li) / den;
    float wi = (lbi * lr - (lbr - 1.f) * li) / den;
    float br = Bre[p * HH + k], bi = Bim[p * HH + k];
    float v = (n < PP) ? (wr * br - wi * bi) : (wr * bi + wi * br);
    W1t[(size_t)n * KK + k] = f2bf(v);
  }
  {
    float v = (k < PP) ? (2.f * Cre[n * PP + k]) : (-2.f * Cim[n * PP + (k - PP)]);
    W2t[(size_t)n * KK + k] = f2bf(v);
  }
  W3t[(size_t)n * KK + k] = f2bf(w2[(size_t)k * HH + n]);
  if (t < PP) {
    float lr = Lre[t], li = Lim[t];
    float st = expf(lstep[t]);
    float er = expf(lr * st);
    float ang = li * st;
    lam_re[t] = er * cosf(ang);
    lam_im[t] = er * sinf(ang);
  }
}

// ---------------- LayerNorm (1 wave per 512-wide row, 4 rows/block) ----------------
__global__ void ln1_kernel(const float* __restrict__ x, const float* __restrict__ sc,
                           const float* __restrict__ bs, unsigned short* __restrict__ xn) {
  int row = blockIdx.x * 4 + (threadIdx.x >> 6);
  int lane = threadIdx.x & 63;
  const float4* xr = (const float4*)(x + (size_t)row * HH) + lane * 2;
  float4 a = xr[0], b = xr[1];
  float s = (a.x + a.y) + (a.z + a.w) + (b.x + b.y) + (b.z + b.w);
  float q = a.x * a.x + a.y * a.y + a.z * a.z + a.w * a.w +
            b.x * b.x + b.y * b.y + b.z * b.z + b.w * b.w;
#pragma unroll
  for (int off = 32; off; off >>= 1) { s += __shfl_xor(s, off); q += __shfl_xor(q, off); }
  float mean = s * (1.f / HH);
  float var = fmaxf(q * (1.f / HH) - mean * mean, 0.f);
  float rstd = rsqrtf(var + 1e-6f);
  const float4* scp = (const float4*)sc + lane * 2;
  const float4* bsp = (const float4*)bs + lane * 2;
  float4 s0 = scp[0], s1 = scp[1], b0 = bsp[0], b1 = bsp[1];
  unsigned short o[8];
  o[0] = f2bf((a.x - mean) * rstd * s0.x + b0.x);
  o[1] = f2bf((a.y - mean) * rstd * s0.y + b0.y);
  o[2] = f2bf((a.z - mean) * rstd * s0.z + b0.z);
  o[3] = f2bf((a.w - mean) * rstd * s0.w + b0.w);
  o[4] = f2bf((b.x - mean) * rstd * s1.x + b1.x);
  o[5] = f2bf((b.y - mean) * rstd * s1.y + b1.y);
  o[6] = f2bf((b.z - mean) * rstd * s1.z + b1.z);
  o[7] = f2bf((b.w - mean) * rstd * s1.w + b1.w);
  uint4 pk;
  pk.x = o[0] | ((unsigned)o[1] << 16);
  pk.y = o[2] | ((unsigned)o[3] << 16);
  pk.z = o[4] | ((unsigned)o[5] << 16);
  pk.w = o[6] | ((unsigned)o[7] << 16);
  *((uint4*)(xn + (size_t)row * HH) + lane) = pk;
}

// LN + GELU: writes y (bf16) and x1 = gelu(y) (bf16)
__global__ void ln2_kernel(const float* __restrict__ ys, const float* __restrict__ sc,
                           const float* __restrict__ bs, unsigned short* __restrict__ y,
                           unsigned short* __restrict__ x1) {
  int row = blockIdx.x * 4 + (threadIdx.x >> 6);
  int lane = threadIdx.x & 63;
  const float4* xr = (const float4*)(ys + (size_t)row * HH) + lane * 2;
  float4 a = xr[0], b = xr[1];
  float s = (a.x + a.y) + (a.z + a.w) + (b.x + b.y) + (b.z + b.w);
  float q = a.x * a.x + a.y * a.y + a.z * a.z + a.w * a.w +
            b.x * b.x + b.y * b.y + b.z * b.z + b.w * b.w;
#pragma unroll
  for (int off = 32; off; off >>= 1) { s += __shfl_xor(s, off); q += __shfl_xor(q, off); }
  float mean = s * (1.f / HH);
  float var = fmaxf(q * (1.f / HH) - mean * mean, 0.f);
  float rstd = rsqrtf(var + 1e-6f);
  const float4* scp = (const float4*)sc + lane * 2;
  const float4* bsp = (const float4*)bs + lane * 2;
  float4 s0 = scp[0], s1 = scp[1], b0 = bsp[0], b1 = bsp[1];
  float v[8] = { a.x, a.y, a.z, a.w, b.x, b.y, b.z, b.w };
  float scv[8] = { s0.x, s0.y, s0.z, s0.w, s1.x, s1.y, s1.z, s1.w };
  float bsv[8] = { b0.x, b0.y, b0.z, b0.w, b1.x, b1.y, b1.z, b1.w };
  unsigned short oy[8], og[8];
#pragma unroll
  for (int j = 0; j < 8; j++) {
    float yv = (v[j] - mean) * rstd * scv[j] + bsv[j];
    oy[j] = f2bf(yv);
    float g = 0.5f * yv * (1.f + tanhf(0.7978845608f * (yv + 0.044715f * yv * yv * yv)));
    og[j] = f2bf(g);
  }
  uint4 py, pg;
  py.x = oy[0] | ((unsigned)oy[1] << 16); py.y = oy[2] | ((unsigned)oy[3] << 16);
  py.z = oy[4] | ((unsigned)oy[5] << 16); py.w = oy[6] | ((unsigned)oy[7] << 16);
  pg.x = og[0] | ((unsigned)og[1] << 16); pg.y = og[2] | ((unsigned)og[3] << 16);
  pg.z = og[4] | ((unsigned)og[5] << 16); pg.w = og[6] | ((unsigned)og[7] << 16);
  *((uint4*)(y  + (size_t)row * HH) + lane) = py;
  *((uint4*)(x1 + (size_t)row * HH) + lane) = pg;
}

// ---------------- bf16 MFMA GEMM: C[m,n] = sum_k A[m,k] * Wt[n,k] ----------------
// 128x128 tile, BK=64, 256 threads = 4 waves (2x2), each wave 64x64 (4x4 of 16x16).
// EPI 0: Cout=f32 raw.  EPI 1: Cout = acc + Dvec[col]*bf(aux16).  EPI 2: z=acc+Dvec[col];
//        Cout = skip + bf(aux16)*sigmoid(z).
template <int EPI>
__global__ __launch_bounds__(256, 2) void gemm_kernel(
    const unsigned short* __restrict__ A, const unsigned short* __restrict__ Wt,
    float* __restrict__ Cout, const float* __restrict__ Dvec,
    const unsigned short* __restrict__ aux16, const float* __restrict__ skip) {
  __shared__ alignas(16) unsigned short lA[128 * 64];
  __shared__ alignas(16) unsigned short lB[128 * 64];
  int tid = threadIdx.x;
  int w = tid >> 6, lane = tid & 63;
  int m0 = blockIdx.y * 128, n0 = blockIdx.x * 128;
  int wr = w >> 1, wc = w & 1;
  f32x4 acc[4][4];
#pragma unroll
  for (int i = 0; i < 4; i++)
#pragma unroll
    for (int j = 0; j < 4; j++) acc[i][j] = (f32x4){0.f, 0.f, 0.f, 0.f};

  for (int kt = 0; kt < KK / 64; ++kt) {
    __syncthreads();
#pragma unroll
    for (int i = 0; i < 4; i++) {  // stage A tile: 128 rows x 64 cols bf16
      int idx = i * 256 + tid;
      int r = idx >> 3, c = idx & 7;
      const unsigned short* g = A + (size_t)(m0 + r) * KK + kt * 64 + c * 8;
      unsigned short* l = &lA[(i * 256 + w * 64) * 8];  // wave-uniform base; HW adds lane*16B
      __builtin_amdgcn_global_load_lds((const __attribute__((address_space(1))) void*)g,
                                       (__attribute__((address_space(3))) void*)l, 16, 0, 0);
    }
#pragma unroll
    for (int i = 0; i < 4; i++) {  // stage Wt tile
      int idx = i * 256 + tid;
      int r = idx >> 3, c = idx & 7;
      const unsigned short* g = Wt + (size_t)(n0 + r) * KK + kt * 64 + c * 8;
      unsigned short* l = &lB[(i * 256 + w * 64) * 8];
      __builtin_amdgcn_global_load_lds((const __attribute__((address_space(1))) void*)g,
                                       (__attribute__((address_space(3))) void*)l, 16, 0, 0);
    }
    __syncthreads();
#pragma unroll
    for (int ks = 0; ks < 2; ++ks) {
      bf16x8 aF[4], bF[4];
#pragma unroll
      for (int m = 0; m < 4; m++)
        aF[m] = *reinterpret_cast<const bf16x8*>(
            &lA[(wr * 64 + m * 16 + (lane & 15)) * 64 + ks * 32 + (lane >> 4) * 8]);
#pragma unroll
      for (int n = 0; n < 4; n++)
        bF[n] = *reinterpret_cast<const bf16x8*>(
            &lB[(wc * 64 + n * 16 + (lane & 15)) * 64 + ks * 32 + (lane >> 4) * 8]);
#pragma unroll
      for (int m = 0; m < 4; m++)
#pragma unroll
        for (int n = 0; n < 4; n++)
          acc[m][n] = __builtin_amdgcn_mfma_f32_16x16x32_bf16(aF[m], bF[n], acc[m][n], 0, 0, 0);
    }
  }
  // epilogue: C/D layout col=lane&15, row=(lane>>4)*4+j  [m89-verified]
  int lr4 = (lane >> 4) * 4, lc = lane & 15;
#pragma unroll
  for (int m = 0; m < 4; m++) {
    int rowb = m0 + wr * 64 + m * 16 + lr4;
#pragma unroll
    for (int n = 0; n < 4; n++) {
      int col = n0 + wc * 64 + n * 16 + lc;
#pragma unroll
      for (int j = 0; j < 4; j++) {
        int row = rowb + j;
        size_t idx = (size_t)row * NN + col;
        float v = acc[m][n][j];
        if (EPI == 0) {
          Cout[idx] = v;
        } else if (EPI == 1) {
          Cout[idx] = v + Dvec[col] * bf2f(aux16[idx]);
        } else {
          float z = v + Dvec[col];
          float sg = 1.f / (1.f + expf(-z));
          Cout[idx] = skip[idx] + bf2f(aux16[idx]) * sg;
        }
      }
    }
  }
}

// ---------------- chunked scan ----------------
// Phase A: per (chunk c, b, p): A = prod a, s = chunk applied to 0.
__global__ void scanA_kernel(const float* __restrict__ Bu, const void* __restrict__ d,
                             const int* __restrict__ dflag, const float* __restrict__ lam_re,
                             const float* __restrict__ lam_im, float* __restrict__ Ar,
                             float* __restrict__ Ai, float* __restrict__ Sr,
                             float* __restrict__ Si) {
  int bx = blockIdx.x;  // c*16 + b
  int c = bx >> 4, b = bx & 15;
  int p = threadIdx.x;
  int fl = *dflag;
  float lr = lam_re[p], li = lam_im[p];
  float Apr = 1.f, Api = 0.f, sr = 0.f, si = 0.f;
  int l0 = c * CLEN;
  for (int j = 0; j < CLEN; j++) {
    int l = l0 + j;
    float kp = keep_val(d, fl, l * BB + b);
    float ar = lr * kp, ai = li * kp;
    size_t ro = (size_t)(l * BB + b) * NN;
    float bur = Bu[ro + p], bui = Bu[ro + PP + p];
    float nsr = ar * sr - ai * si + bur;
    float nsi = ar * si + ai * sr + bui;
    sr = nsr; si = nsi;
    float nar = ar * Apr - ai * Api;
    float nai = ar * Api + ai * Apr;
    Apr = nar; Api = nai;
  }
  int o = bx * PP + p;
  Ar[o] = Apr; Ai[o] = Api; Sr[o] = sr; Si[o] = si;
}

// Phase B: sequential chunk combine per (b,p); writes carries + final hidden outputs.
__global__ void scanB_kernel(const float* __restrict__ hr0, const float* __restrict__ hi0,
                             const float* __restrict__ Ar, const float* __restrict__ Ai,
                             const float* __restrict__ Sr, const float* __restrict__ Si,
                             float* __restrict__ Cr, float* __restrict__ Ci,
                             float* __restrict__ outHid) {
  int b = blockIdx.x;
  int p = threadIdx.x;
  float cr = hr0[b * PP + p], ci = hi0[b * PP + p];
  for (int c = 0; c < NC; c++) {
    int o = (c * BB + b) * PP + p;
    Cr[o] = cr; Ci[o] = ci;
    float ar = Ar[o], ai = Ai[o];
    float nr = ar * cr - ai * ci + Sr[o];
    float ni = ar * ci + ai * cr + Si[o];
    cr = nr; ci = ni;
  }
  outHid[b * PP + p] = cr;                 // new_hidden.real
  outHid[BB * PP + b * PP + p] = ci;       // new_hidden.imag
}

// Phase C: replay with carry, emit xs (bf16, concat re|im).
__global__ void scanC_kernel(const float* __restrict__ Bu, const void* __restrict__ d,
                             const int* __restrict__ dflag, const float* __restrict__ lam_re,
                             const float* __restrict__ lam_im, const float* __restrict__ Cr,
                             const float* __restrict__ Ci, unsigned short* __restrict__ xs) {
  int bx = blockIdx.x;
  int c = bx >> 4, b = bx & 15;
  int p = threadIdx.x;
  int fl = *dflag;
  float lr = lam_re[p], li = lam_im[p];
  float hr = Cr[bx * PP + p], hi = Ci[bx * PP + p];
  int l0 = c * CLEN;
  for (int j = 0; j < CLEN; j++) {
    int l = l0 + j;
    float kp = keep_val(d, fl, l * BB + b);
    float ar = lr * kp, ai = li * kp;
    size_t ro = (size_t)(l * BB + b) * NN;
    float bur = Bu[ro + p], bui = Bu[ro + PP + p];
    float nhr = ar * hr - ai * hi + bur;
    float nhi = ar * hi + ai * hr + bui;
    hr = nhr; hi = nhi;
    xs[ro + p] = f2bf(hr);
    xs[ro + PP + p] = f2bf(hi);
  }
}

// ---------------- launcher ----------------
extern "C" void kernel_launch(void* const* d_in, const int* in_sizes, int n_in,
                              void* d_out, int out_size, void* d_ws, size_t ws_size,
                              hipStream_t stream) {
  const float* x    = (const float*)d_in[0];
  const void*  dmask= d_in[1];
  const float* hidr = (const float*)d_in[2];
  const float* hidi = (const float*)d_in[3];
  const float* Lre  = (const float*)d_in[4];
  const float* Lim  = (const float*)d_in[5];
  const float* Bre  = (const float*)d_in[6];
  const float* Bim  = (const float*)d_in[7];
  const float* Cre  = (const float*)d_in[8];
  const float* Cim  = (const float*)d_in[9];
  const float* Dv   = (const float*)d_in[10];
  const float* lst  = (const float*)d_in[11];
  const float* lsc  = (const float*)d_in[12];
  const float* lbs  = (const float*)d_in[13];
  const float* w2   = (const float*)d_in[14];
  const float* b2   = (const float*)d_in[15];
  float* out = (float*)d_out;

  char* ws = (char*)d_ws;
  size_t off = 0;
  auto alloc = [&](size_t bytes) -> void* {
    void* p = ws + off;
    off += (bytes + 255) & ~(size_t)255;
    return p;
  };
  unsigned short* xn  = (unsigned short*)alloc((size_t)MM * KK * 2);  // 32MB; reused as y
  unsigned short* xs  = (unsigned short*)alloc((size_t)MM * KK * 2);  // 32MB; reused as x1
  float* Bu           = (float*)alloc((size_t)MM * NN * 4);           // 64MB; reused as ys
  unsigned short* W1t = (unsigned short*)alloc((size_t)NN * KK * 2);
  unsigned short* W2t = (unsigned short*)alloc((size_t)NN * KK * 2);
  unsigned short* W3t = (unsigned short*)alloc((size_t)NN * KK * 2);
  float* lam_re = (float*)alloc(PP * 4);
  float* lam_im = (float*)alloc(PP * 4);
  float* Ar = (float*)alloc((size_t)NC * BB * PP * 4);
  float* Ai = (float*)alloc((size_t)NC * BB * PP * 4);
  float* Sr = (float*)alloc((size_t)NC * BB * PP * 4);
  float* Si = (float*)alloc((size_t)NC * BB * PP * 4);
  float* Cr = (float*)alloc((size_t)NC * BB * PP * 4);
  float* Ci = (float*)alloc((size_t)NC * BB * PP * 4);
  int* dflag = (int*)alloc(256);
  unsigned short* y  = xn;   // reuse after GEMM2 consumed xn
  unsigned short* x1 = xs;   // reuse after GEMM2 consumed xs
  float* ysb = Bu;           // reuse after scan consumed Bu

  detect_kernel<<<1, 256, 0, stream>>>((const unsigned int*)dmask, dflag);
  precompute_kernel<<<1024, 256, 0, stream>>>(Lre, Lim, Bre, Bim, Cre, Cim, lst, w2,
                                              W1t, W2t, W3t, lam_re, lam_im);
  ln1_kernel<<<MM / 4, 256, 0, stream>>>(x, lsc, lbs, xn);
  gemm_kernel<0><<<dim3(4, 256), 256, 0, stream>>>(xn, W1t, Bu, nullptr, nullptr, nullptr);
  scanA_kernel<<<NC * BB, 256, 0, stream>>>(Bu, dmask, dflag, lam_re, lam_im, Ar, Ai, Sr, Si);
  scanB_kernel<<<BB, 256, 0, stream>>>(hidr, hidi, Ar, Ai, Sr, Si, Cr, Ci, out);
  scanC_kernel<<<NC * BB, 256, 0, stream>>>(Bu, dmask, dflag, lam_re, lam_im, Cr, Ci, xs);
  gemm_kernel<1><<<dim3(4, 256), 256, 0, stream>>>(xs, W2t, ysb, Dv, xn, nullptr);
  ln2_kernel<<<MM / 4, 256, 0, stream>>>(ysb, lsc, lbs, y, x1);
  gemm_kernel<2><<<dim3(4, 256), 256, 0, stream>>>(x1, W3t, out + 2 * BB * PP, b2, y, x);
}

// Round 2
// 221.638 us; speedup vs baseline: 1.0498x; 1.0498x over previous
//
#include <hip/hip_runtime.h>

// ---------------- problem constants ----------------
#define LL 2048
#define BB 16
#define HH 512
#define PP 256
#define MM (LL*BB)   // 32768 rows
#define NN 512       // all GEMMs: N=512
#define KK 512       // all GEMMs: K=512
#define NC 64        // scan chunks
#define CLEN 32      // chunk length (NC*CLEN == LL)

typedef __bf16 bf16x8 __attribute__((ext_vector_type(8)));
typedef float  f32x4  __attribute__((ext_vector_type(4)));

__device__ __forceinline__ unsigned short f2bf(float f) {
  unsigned u = __builtin_bit_cast(unsigned, f);
  u = (u + 0x7fffu + ((u >> 16) & 1u)) >> 16;   // RNE
  return (unsigned short)u;
}
__device__ __forceinline__ float bf2f(unsigned short s) {
  unsigned u = ((unsigned)s) << 16;
  return __builtin_bit_cast(float, u);
}

// ---------------- dtype detection for `d` (bool input; harness dtype ambiguous) ----
__global__ void detect_kernel(const unsigned int* __restrict__ dw, int* __restrict__ flag) {
  __shared__ int sInt, sFloat;
  if (threadIdx.x == 0) { sInt = 1; sFloat = 1; }
  __syncthreads();
  int allInt = 1, allFloat = 1;
  for (int i = threadIdx.x; i < 8192; i += 256) {
    unsigned v = dw[i];
    if (v > 1u) allInt = 0;
    if (v != 0u && v != 0x3f800000u) allFloat = 0;
  }
  if (!allInt) atomicAnd(&sInt, 0);
  if (!allFloat) atomicAnd(&sFloat, 0);
  __syncthreads();
  if (threadIdx.x == 0) *flag = sInt ? 0 : (sFloat ? 1 : 2);
}

__device__ __forceinline__ float keep_val(const void* d, int flag, int idx) {
  if (flag == 0) return 1.f - (float)((const int*)d)[idx];
  if (flag == 1) return 1.f - ((const float*)d)[idx];
  return 1.f - (float)((const unsigned char*)d)[idx];
}

// ---------------- weight precompute ----------------
__global__ void precompute_kernel(
    const float* __restrict__ Lre, const float* __restrict__ Lim,
    const float* __restrict__ Bre, const float* __restrict__ Bim,
    const float* __restrict__ Cre, const float* __restrict__ Cim,
    const float* __restrict__ lstep, const float* __restrict__ w2,
    unsigned short* __restrict__ W1t, unsigned short* __restrict__ W2t,
    unsigned short* __restrict__ W3t, float* __restrict__ lam_re,
    float* __restrict__ lam_im) {
  int t = blockIdx.x * 256 + threadIdx.x;   // 0..262143
  int k = t & (KK - 1);
  int n = t >> 9;
  {
    int p = n & (PP - 1);
    float lr = Lre[p], li = Lim[p];
    float st = expf(lstep[p]);
    float er = expf(lr * st);
    float ang = li * st;
    float lbr = er * cosf(ang), lbi = er * sinf(ang);
    float den = lr * lr + li * li;
    float wr = ((lbr - 1.f) * lr + lbi * li) / den;
    float wi = (lbi * lr - (lbr - 1.f) * li) / den;
    float br = Bre[p * HH + k], bi = Bim[p * HH + k];
    float v = (n < PP) ? (wr * br - wi * bi) : (wr * bi + wi * br);
    W1t[(size_t)n * KK + k] = f2bf(v);
  }
  {
    float v = (k < PP) ? (2.f * Cre[n * PP + k]) : (-2.f * Cim[n * PP + (k - PP)]);
    W2t[(size_t)n * KK + k] = f2bf(v);
  }
  W3t[(size_t)n * KK + k] = f2bf(w2[(size_t)k * HH + n]);
  if (t < PP) {
    float lr = Lre[t], li = Lim[t];
    float st = expf(lstep[t]);
    float er = expf(lr * st);
    float ang = li * st;
    lam_re[t] = er * cosf(ang);
    lam_im[t] = er * sinf(ang);
  }
}

// ---------------- LayerNorm (1 wave per 512-wide row, 4 rows/block) ----------------
__global__ void ln1_kernel(const float* __restrict__ x, const float* __restrict__ sc,
                           const float* __restrict__ bs, unsigned short* __restrict__ xn) {
  int row = blockIdx.x * 4 + (threadIdx.x >> 6);
  int lane = threadIdx.x & 63;
  const float4* xr = (const float4*)(x + (size_t)row * HH) + lane * 2;
  float4 a = xr[0], b = xr[1];
  float s = (a.x + a.y) + (a.z + a.w) + (b.x + b.y) + (b.z + b.w);
  float q = a.x * a.x + a.y * a.y + a.z * a.z + a.w * a.w +
            b.x * b.x + b.y * b.y + b.z * b.z + b.w * b.w;
#pragma unroll
  for (int off = 32; off; off >>= 1) { s += __shfl_xor(s, off); q += __shfl_xor(q, off); }
  float mean = s * (1.f / HH);
  float var = fmaxf(q * (1.f / HH) - mean * mean, 0.f);
  float rstd = rsqrtf(var + 1e-6f);
  const float4* scp = (const float4*)sc + lane * 2;
  const float4* bsp = (const float4*)bs + lane * 2;
  float4 s0 = scp[0], s1 = scp[1], b0 = bsp[0], b1 = bsp[1];
  unsigned short o[8];
  o[0] = f2bf((a.x - mean) * rstd * s0.x + b0.x);
  o[1] = f2bf((a.y - mean) * rstd * s0.y + b0.y);
  o[2] = f2bf((a.z - mean) * rstd * s0.z + b0.z);
  o[3] = f2bf((a.w - mean) * rstd * s0.w + b0.w);
  o[4] = f2bf((b.x - mean) * rstd * s1.x + b1.x);
  o[5] = f2bf((b.y - mean) * rstd * s1.y + b1.y);
  o[6] = f2bf((b.z - mean) * rstd * s1.z + b1.z);
  o[7] = f2bf((b.w - mean) * rstd * s1.w + b1.w);
  uint4 pk;
  pk.x = o[0] | ((unsigned)o[1] << 16);
  pk.y = o[2] | ((unsigned)o[3] << 16);
  pk.z = o[4] | ((unsigned)o[5] << 16);
  pk.w = o[6] | ((unsigned)o[7] << 16);
  *((uint4*)(xn + (size_t)row * HH) + lane) = pk;
}

// LN + GELU: writes y (bf16) and x1 = gelu(y) (bf16)
__global__ void ln2_kernel(const float* __restrict__ ys, const float* __restrict__ sc,
                           const float* __restrict__ bs, unsigned short* __restrict__ y,
                           unsigned short* __restrict__ x1) {
  int row = blockIdx.x * 4 + (threadIdx.x >> 6);
  int lane = threadIdx.x & 63;
  const float4* xr = (const float4*)(ys + (size_t)row * HH) + lane * 2;
  float4 a = xr[0], b = xr[1];
  float s = (a.x + a.y) + (a.z + a.w) + (b.x + b.y) + (b.z + b.w);
  float q = a.x * a.x + a.y * a.y + a.z * a.z + a.w * a.w +
            b.x * b.x + b.y * b.y + b.z * b.z + b.w * b.w;
#pragma unroll
  for (int off = 32; off; off >>= 1) { s += __shfl_xor(s, off); q += __shfl_xor(q, off); }
  float mean = s * (1.f / HH);
  float var = fmaxf(q * (1.f / HH) - mean * mean, 0.f);
  float rstd = rsqrtf(var + 1e-6f);
  const float4* scp = (const float4*)sc + lane * 2;
  const float4* bsp = (const float4*)bs + lane * 2;
  float4 s0 = scp[0], s1 = scp[1], b0 = bsp[0], b1 = bsp[1];
  float v[8] = { a.x, a.y, a.z, a.w, b.x, b.y, b.z, b.w };
  float scv[8] = { s0.x, s0.y, s0.z, s0.w, s1.x, s1.y, s1.z, s1.w };
  float bsv[8] = { b0.x, b0.y, b0.z, b0.w, b1.x, b1.y, b1.z, b1.w };
  unsigned short oy[8], og[8];
#pragma unroll
  for (int j = 0; j < 8; j++) {
    float yv = (v[j] - mean) * rstd * scv[j] + bsv[j];
    oy[j] = f2bf(yv);
    float g = 0.5f * yv * (1.f + tanhf(0.7978845608f * (yv + 0.044715f * yv * yv * yv)));
    og[j] = f2bf(g);
  }
  uint4 py, pg;
  py.x = oy[0] | ((unsigned)oy[1] << 16); py.y = oy[2] | ((unsigned)oy[3] << 16);
  py.z = oy[4] | ((unsigned)oy[5] << 16); py.w = oy[6] | ((unsigned)oy[7] << 16);
  pg.x = og[0] | ((unsigned)og[1] << 16); pg.y = og[2] | ((unsigned)og[3] << 16);
  pg.z = og[4] | ((unsigned)og[5] << 16); pg.w = og[6] | ((unsigned)og[7] << 16);
  *((uint4*)(y  + (size_t)row * HH) + lane) = py;
  *((uint4*)(x1 + (size_t)row * HH) + lane) = pg;
}

// ---------------- bf16 MFMA GEMM: C[m,n] = sum_k A[m,k] * Wt[n,k] ----------------
// 128x128 tile, BK=64, 256 threads = 4 waves (2x2), each wave 64x64 (4x4 of 16x16).
// T1: XCD-grouped block swizzle — all 4 n-blocks of an m-panel on one XCD (A fetched ~1x).
// T2: both-sides XOR swizzle (rule #21) — linear global_load_lds dest, inverse-swizzled
//     global SOURCE (chunk c ^= r&7), swizzled fragment READ (slot ^= row&7).
template <int EPI>
__global__ __launch_bounds__(256, 4) void gemm_kernel(
    const unsigned short* __restrict__ A, const unsigned short* __restrict__ Wt,
    float* __restrict__ Cout, const float* __restrict__ Dvec,
    const unsigned short* __restrict__ aux16, const float* __restrict__ skip) {
  __shared__ alignas(16) unsigned short lA[128 * 64];
  __shared__ alignas(16) unsigned short lB[128 * 64];
  int tid = threadIdx.x;
  int w = tid >> 6, lane = tid & 63;
  // 1024 blocks; xcd = wgid&7 (round-robin dispatch); XCD k owns m-panels [k*32,(k+1)*32)
  int wgid = blockIdx.x;
  int xcd = wgid & 7, idx = wgid >> 3;          // idx 0..127
  int m0 = (xcd * 32 + (idx >> 2)) * 128;       // m-panel
  int n0 = (idx & 3) * 128;                     // 4 n-blocks adjacent in dispatch, same XCD
  int wr = w >> 1, wc = w & 1;
  f32x4 acc[4][4];
#pragma unroll
  for (int i = 0; i < 4; i++)
#pragma unroll
    for (int j = 0; j < 4; j++) acc[i][j] = (f32x4){0.f, 0.f, 0.f, 0.f};

  for (int kt = 0; kt < KK / 64; ++kt) {
    __syncthreads();
#pragma unroll
    for (int i = 0; i < 4; i++) {  // stage A tile: 128 rows x 64 cols bf16
      int sidx = i * 256 + tid;
      int r = sidx >> 3, c = sidx & 7;
      int cs = c ^ (r & 7);                     // inverse-swizzled source chunk
      const unsigned short* g = A + (size_t)(m0 + r) * KK + kt * 64 + cs * 8;
      unsigned short* l = &lA[(i * 256 + w * 64) * 8];  // linear dest; HW adds lane*16B
      __builtin_amdgcn_global_load_lds((const __attribute__((address_space(1))) void*)g,
                                       (__attribute__((address_space(3))) void*)l, 16, 0, 0);
    }
#pragma unroll
    for (int i = 0; i < 4; i++) {  // stage Wt tile
      int sidx = i * 256 + tid;
      int r = sidx >> 3, c = sidx & 7;
      int cs = c ^ (r & 7);
      const unsigned short* g = Wt + (size_t)(n0 + r) * KK + kt * 64 + cs * 8;
      unsigned short* l = &lB[(i * 256 + w * 64) * 8];
      __builtin_amdgcn_global_load_lds((const __attribute__((address_space(1))) void*)g,
                                       (__attribute__((address_space(3))) void*)l, 16, 0, 0);
    }
    __syncthreads();
#pragma unroll
    for (int ks = 0; ks < 2; ++ks) {
      bf16x8 aF[4], bF[4];
#pragma unroll
      for (int m = 0; m < 4; m++) {
        int row = wr * 64 + m * 16 + (lane & 15);
        int s = ks * 4 + (lane >> 4);
        aF[m] = *reinterpret_cast<const bf16x8*>(&lA[row * 64 + (s ^ (row & 7)) * 8]);
      }
#pragma unroll
      for (int n = 0; n < 4; n++) {
        int row = wc * 64 + n * 16 + (lane & 15);
        int s = ks * 4 + (lane >> 4);
        bF[n] = *reinterpret_cast<const bf16x8*>(&lB[row * 64 + (s ^ (row & 7)) * 8]);
      }
#pragma unroll
      for (int m = 0; m < 4; m++)
#pragma unroll
        for (int n = 0; n < 4; n++)
          acc[m][n] = __builtin_amdgcn_mfma_f32_16x16x32_bf16(aF[m], bF[n], acc[m][n], 0, 0, 0);
    }
  }
  // epilogue: C/D layout col=lane&15, row=(lane>>4)*4+j  [m89-verified]
  int lr4 = (lane >> 4) * 4, lc = lane & 15;
#pragma unroll
  for (int m = 0; m < 4; m++) {
    int rowb = m0 + wr * 64 + m * 16 + lr4;
#pragma unroll
    for (int n = 0; n < 4; n++) {
      int col = n0 + wc * 64 + n * 16 + lc;
#pragma unroll
      for (int j = 0; j < 4; j++) {
        int row = rowb + j;
        size_t idxo = (size_t)row * NN + col;
        float v = acc[m][n][j];
        if (EPI == 0) {
          Cout[idxo] = v;
        } else if (EPI == 1) {
          Cout[idxo] = v + Dvec[col] * bf2f(aux16[idxo]);
        } else {
          float z = v + Dvec[col];
          float sg = 1.f / (1.f + expf(-z));
          Cout[idxo] = skip[idxo] + bf2f(aux16[idxo]) * sg;
        }
      }
    }
  }
}

// ---------------- chunked scan ----------------
__global__ void scanA_kernel(const float* __restrict__ Bu, const void* __restrict__ d,
                             const int* __restrict__ dflag, const float* __restrict__ lam_re,
                             const float* __restrict__ lam_im, float* __restrict__ Ar,
                             float* __restrict__ Ai, float* __restrict__ Sr,
                             float* __restrict__ Si) {
  int bx = blockIdx.x;  // c*16 + b
  int c = bx >> 4, b = bx & 15;
  int p = threadIdx.x;
  int fl = *dflag;
  float lr = lam_re[p], li = lam_im[p];
  float Apr = 1.f, Api = 0.f, sr = 0.f, si = 0.f;
  int l0 = c * CLEN;
  for (int j = 0; j < CLEN; j++) {
    int l = l0 + j;
    float kp = keep_val(d, fl, l * BB + b);
    float ar = lr * kp, ai = li * kp;
    size_t ro = (size_t)(l * BB + b) * NN;
    float bur = Bu[ro + p], bui = Bu[ro + PP + p];
    float nsr = ar * sr - ai * si + bur;
    float nsi = ar * si + ai * sr + bui;
    sr = nsr; si = nsi;
    float nar = ar * Apr - ai * Api;
    float nai = ar * Api + ai * Apr;
    Apr = nar; Api = nai;
  }
  int o = bx * PP + p;
  Ar[o] = Apr; Ai[o] = Api; Sr[o] = sr; Si[o] = si;
}

__global__ void scanB_kernel(const float* __restrict__ hr0, const float* __restrict__ hi0,
                             const float* __restrict__ Ar, const float* __restrict__ Ai,
                             const float* __restrict__ Sr, const float* __restrict__ Si,
                             float* __restrict__ Cr, float* __restrict__ Ci,
                             float* __restrict__ outHid) {
  int b = blockIdx.x;
  int p = threadIdx.x;
  float cr = hr0[b * PP + p], ci = hi0[b * PP + p];
  for (int c = 0; c < NC; c++) {
    int o = (c * BB + b) * PP + p;
    Cr[o] = cr; Ci[o] = ci;
    float ar = Ar[o], ai = Ai[o];
    float nr = ar * cr - ai * ci + Sr[o];
    float ni = ar * ci + ai * cr + Si[o];
    cr = nr; ci = ni;
  }
  outHid[b * PP + p] = cr;                 // new_hidden.real
  outHid[BB * PP + b * PP + p] = ci;       // new_hidden.imag
}

__global__ void scanC_kernel(const float* __restrict__ Bu, const void* __restrict__ d,
                             const int* __restrict__ dflag, const float* __restrict__ lam_re,
                             const float* __restrict__ lam_im, const float* __restrict__ Cr,
                             const float* __restrict__ Ci, unsigned short* __restrict__ xs) {
  int bx = blockIdx.x;
  int c = bx >> 4, b = bx & 15;
  int p = threadIdx.x;
  int fl = *dflag;
  float lr = lam_re[p], li = lam_im[p];
  float hr = Cr[bx * PP + p], hi = Ci[bx * PP + p];
  int l0 = c * CLEN;
  for (int j = 0; j < CLEN; j++) {
    int l = l0 + j;
    float kp = keep_val(d, fl, l * BB + b);
    float ar = lr * kp, ai = li * kp;
    size_t ro = (size_t)(l * BB + b) * NN;
    float bur = Bu[ro + p], bui = Bu[ro + PP + p];
    float nhr = ar * hr - ai * hi + bur;
    float nhi = ar * hi + ai * hr + bui;
    hr = nhr; hi = nhi;
    xs[ro + p] = f2bf(hr);
    xs[ro + PP + p] = f2bf(hi);
  }
}

// ---------------- launcher ----------------
extern "C" void kernel_launch(void* const* d_in, const int* in_sizes, int n_in,
                              void* d_out, int out_size, void* d_ws, size_t ws_size,
                              hipStream_t stream) {
  const float* x    = (const float*)d_in[0];
  const void*  dmask= d_in[1];
  const float* hidr = (const float*)d_in[2];
  const float* hidi = (const float*)d_in[3];
  const float* Lre  = (const float*)d_in[4];
  const float* Lim  = (const float*)d_in[5];
  const float* Bre  = (const float*)d_in[6];
  const float* Bim  = (const float*)d_in[7];
  const float* Cre  = (const float*)d_in[8];
  const float* Cim  = (const float*)d_in[9];
  const float* Dv   = (const float*)d_in[10];
  const float* lst  = (const float*)d_in[11];
  const float* lsc  = (const float*)d_in[12];
  const float* lbs  = (const float*)d_in[13];
  const float* w2   = (const float*)d_in[14];
  const float* b2   = (const float*)d_in[15];
  float* out = (float*)d_out;

  char* ws = (char*)d_ws;
  size_t off = 0;
  auto alloc = [&](size_t bytes) -> void* {
    void* p = ws + off;
    off += (bytes + 255) & ~(size_t)255;
    return p;
  };
  unsigned short* xn  = (unsigned short*)alloc((size_t)MM * KK * 2);  // 32MB; reused as y
  unsigned short* xs  = (unsigned short*)alloc((size_t)MM * KK * 2);  // 32MB; reused as x1
  float* Bu           = (float*)alloc((size_t)MM * NN * 4);           // 64MB; reused as ys
  unsigned short* W1t = (unsigned short*)alloc((size_t)NN * KK * 2);
  unsigned short* W2t = (unsigned short*)alloc((size_t)NN * KK * 2);
  unsigned short* W3t = (unsigned short*)alloc((size_t)NN * KK * 2);
  float* lam_re = (float*)alloc(PP * 4);
  float* lam_im = (float*)alloc(PP * 4);
  float* Ar = (float*)alloc((size_t)NC * BB * PP * 4);
  float* Ai = (float*)alloc((size_t)NC * BB * PP * 4);
  float* Sr = (float*)alloc((size_t)NC * BB * PP * 4);
  float* Si = (float*)alloc((size_t)NC * BB * PP * 4);
  float* Cr = (float*)alloc((size_t)NC * BB * PP * 4);
  float* Ci = (float*)alloc((size_t)NC * BB * PP * 4);
  int* dflag = (int*)alloc(256);
  unsigned short* y  = xn;   // reuse after GEMM2 consumed xn
  unsigned short* x1 = xs;   // reuse after GEMM2 consumed xs
  float* ysb = Bu;           // reuse after scan consumed Bu

  detect_kernel<<<1, 256, 0, stream>>>((const unsigned int*)dmask, dflag);
  precompute_kernel<<<1024, 256, 0, stream>>>(Lre, Lim, Bre, Bim, Cre, Cim, lst, w2,
                                              W1t, W2t, W3t, lam_re, lam_im);
  ln1_kernel<<<MM / 4, 256, 0, stream>>>(x, lsc, lbs, xn);
  gemm_kernel<0><<<1024, 256, 0, stream>>>(xn, W1t, Bu, nullptr, nullptr, nullptr);
  scanA_kernel<<<NC * BB, 256, 0, stream>>>(Bu, dmask, dflag, lam_re, lam_im, Ar, Ai, Sr, Si);
  scanB_kernel<<<BB, 256, 0, stream>>>(hidr, hidi, Ar, Ai, Sr, Si, Cr, Ci, out);
  scanC_kernel<<<NC * BB, 256, 0, stream>>>(Bu, dmask, dflag, lam_re, lam_im, Cr, Ci, xs);
  gemm_kernel<1><<<1024, 256, 0, stream>>>(xs, W2t, ysb, Dv, xn, nullptr);
  ln2_kernel<<<MM / 4, 256, 0, stream>>>(ysb, lsc, lbs, y, x1);
  gemm_kernel<2><<<1024, 256, 0, stream>>>(x1, W3t, out + 2 * BB * PP, b2, y, x);
}

// Round 3
// 196.169 us; speedup vs baseline: 1.1861x; 1.1298x over previous
//
#include <hip/hip_runtime.h>

// ---------------- problem constants ----------------
#define LL 2048
#define BB 16
#define HH 512
#define PP 256
#define MM (LL*BB)   // 32768 rows
#define NN 512       // all GEMMs: N=512
#define KK 512       // all GEMMs: K=512
#define NC 64        // scan chunks
#define CLEN 32      // chunk length (NC*CLEN == LL)
#define NKT (KK/64)  // 8 K-steps

typedef __bf16 bf16x8 __attribute__((ext_vector_type(8)));
typedef float  f32x4  __attribute__((ext_vector_type(4)));

__device__ __forceinline__ unsigned short f2bf(float f) {
  unsigned u = __builtin_bit_cast(unsigned, f);
  u = (u + 0x7fffu + ((u >> 16) & 1u)) >> 16;   // RNE
  return (unsigned short)u;
}
__device__ __forceinline__ float bf2f(unsigned short s) {
  unsigned u = ((unsigned)s) << 16;
  return __builtin_bit_cast(float, u);
}

// ---------------- dtype detection for `d` (bool input; harness dtype ambiguous) ----
__global__ void detect_kernel(const unsigned int* __restrict__ dw, int* __restrict__ flag) {
  __shared__ int sInt, sFloat;
  if (threadIdx.x == 0) { sInt = 1; sFloat = 1; }
  __syncthreads();
  int allInt = 1, allFloat = 1;
  for (int i = threadIdx.x; i < 8192; i += 256) {
    unsigned v = dw[i];
    if (v > 1u) allInt = 0;
    if (v != 0u && v != 0x3f800000u) allFloat = 0;
  }
  if (!allInt) atomicAnd(&sInt, 0);
  if (!allFloat) atomicAnd(&sFloat, 0);
  __syncthreads();
  if (threadIdx.x == 0) *flag = sInt ? 0 : (sFloat ? 1 : 2);
}

__device__ __forceinline__ float keep_val(const void* d, int flag, int idx) {
  if (flag == 0) return 1.f - (float)((const int*)d)[idx];
  if (flag == 1) return 1.f - ((const float*)d)[idx];
  return 1.f - (float)((const unsigned char*)d)[idx];
}

// ---------------- weight precompute ----------------
__global__ void precompute_kernel(
    const float* __restrict__ Lre, const float* __restrict__ Lim,
    const float* __restrict__ Bre, const float* __restrict__ Bim,
    const float* __restrict__ Cre, const float* __restrict__ Cim,
    const float* __restrict__ lstep, const float* __restrict__ w2,
    unsigned short* __restrict__ W1t, unsigned short* __restrict__ W2t,
    unsigned short* __restrict__ W3t, float* __restrict__ lam_re,
    float* __restrict__ lam_im) {
  int t = blockIdx.x * 256 + threadIdx.x;   // 0..262143
  int k = t & (KK - 1);
  int n = t >> 9;
  {
    int p = n & (PP - 1);
    float lr = Lre[p], li = Lim[p];
    float st = expf(lstep[p]);
    float er = expf(lr * st);
    float ang = li * st;
    float lbr = er * cosf(ang), lbi = er * sinf(ang);
    float den = lr * lr + li * li;
    float wr = ((lbr - 1.f) * lr + lbi * li) / den;
    float wi = (lbi * lr - (lbr - 1.f) * li) / den;
    float br = Bre[p * HH + k], bi = Bim[p * HH + k];
    float v = (n < PP) ? (wr * br - wi * bi) : (wr * bi + wi * br);
    W1t[(size_t)n * KK + k] = f2bf(v);
  }
  {
    float v = (k < PP) ? (2.f * Cre[n * PP + k]) : (-2.f * Cim[n * PP + (k - PP)]);
    W2t[(size_t)n * KK + k] = f2bf(v);
  }
  W3t[(size_t)n * KK + k] = f2bf(w2[(size_t)k * HH + n]);
  if (t < PP) {
    float lr = Lre[t], li = Lim[t];
    float st = expf(lstep[t]);
    float er = expf(lr * st);
    float ang = li * st;
    lam_re[t] = er * cosf(ang);
    lam_im[t] = er * sinf(ang);
  }
}

// ---------------- LayerNorm (1 wave per 512-wide row, 4 rows/block) ----------------
__global__ void ln1_kernel(const float* __restrict__ x, const float* __restrict__ sc,
                           const float* __restrict__ bs, unsigned short* __restrict__ xn) {
  int row = blockIdx.x * 4 + (threadIdx.x >> 6);
  int lane = threadIdx.x & 63;
  const float4* xr = (const float4*)(x + (size_t)row * HH) + lane * 2;
  float4 a = xr[0], b = xr[1];
  float s = (a.x + a.y) + (a.z + a.w) + (b.x + b.y) + (b.z + b.w);
  float q = a.x * a.x + a.y * a.y + a.z * a.z + a.w * a.w +
            b.x * b.x + b.y * b.y + b.z * b.z + b.w * b.w;
#pragma unroll
  for (int off = 32; off; off >>= 1) { s += __shfl_xor(s, off); q += __shfl_xor(q, off); }
  float mean = s * (1.f / HH);
  float var = fmaxf(q * (1.f / HH) - mean * mean, 0.f);
  float rstd = rsqrtf(var + 1e-6f);
  const float4* scp = (const float4*)sc + lane * 2;
  const float4* bsp = (const float4*)bs + lane * 2;
  float4 s0 = scp[0], s1 = scp[1], b0 = bsp[0], b1 = bsp[1];
  unsigned short o[8];
  o[0] = f2bf((a.x - mean) * rstd * s0.x + b0.x);
  o[1] = f2bf((a.y - mean) * rstd * s0.y + b0.y);
  o[2] = f2bf((a.z - mean) * rstd * s0.z + b0.z);
  o[3] = f2bf((a.w - mean) * rstd * s0.w + b0.w);
  o[4] = f2bf((b.x - mean) * rstd * s1.x + b1.x);
  o[5] = f2bf((b.y - mean) * rstd * s1.y + b1.y);
  o[6] = f2bf((b.z - mean) * rstd * s1.z + b1.z);
  o[7] = f2bf((b.w - mean) * rstd * s1.w + b1.w);
  uint4 pk;
  pk.x = o[0] | ((unsigned)o[1] << 16);
  pk.y = o[2] | ((unsigned)o[3] << 16);
  pk.z = o[4] | ((unsigned)o[5] << 16);
  pk.w = o[6] | ((unsigned)o[7] << 16);
  *((uint4*)(xn + (size_t)row * HH) + lane) = pk;
}

// LN + GELU: reads ys (bf16), writes y (bf16) and x1 = gelu(y) (bf16)
__global__ void ln2_kernel(const unsigned short* __restrict__ ys, const float* __restrict__ sc,
                           const float* __restrict__ bs, unsigned short* __restrict__ y,
                           unsigned short* __restrict__ x1) {
  int row = blockIdx.x * 4 + (threadIdx.x >> 6);
  int lane = threadIdx.x & 63;
  uint4 pin = *((const uint4*)(ys + (size_t)row * HH) + lane);
  float v[8];
  v[0] = bf2f((unsigned short)(pin.x & 0xffff)); v[1] = bf2f((unsigned short)(pin.x >> 16));
  v[2] = bf2f((unsigned short)(pin.y & 0xffff)); v[3] = bf2f((unsigned short)(pin.y >> 16));
  v[4] = bf2f((unsigned short)(pin.z & 0xffff)); v[5] = bf2f((unsigned short)(pin.z >> 16));
  v[6] = bf2f((unsigned short)(pin.w & 0xffff)); v[7] = bf2f((unsigned short)(pin.w >> 16));
  float s = 0.f, q = 0.f;
#pragma unroll
  for (int j = 0; j < 8; j++) { s += v[j]; q += v[j] * v[j]; }
#pragma unroll
  for (int off = 32; off; off >>= 1) { s += __shfl_xor(s, off); q += __shfl_xor(q, off); }
  float mean = s * (1.f / HH);
  float var = fmaxf(q * (1.f / HH) - mean * mean, 0.f);
  float rstd = rsqrtf(var + 1e-6f);
  const float4* scp = (const float4*)sc + lane * 2;
  const float4* bsp = (const float4*)bs + lane * 2;
  float4 s0 = scp[0], s1 = scp[1], b0 = bsp[0], b1 = bsp[1];
  float scv[8] = { s0.x, s0.y, s0.z, s0.w, s1.x, s1.y, s1.z, s1.w };
  float bsv[8] = { b0.x, b0.y, b0.z, b0.w, b1.x, b1.y, b1.z, b1.w };
  unsigned short oy[8], og[8];
#pragma unroll
  for (int j = 0; j < 8; j++) {
    float yv = (v[j] - mean) * rstd * scv[j] + bsv[j];
    oy[j] = f2bf(yv);
    float g = 0.5f * yv * (1.f + tanhf(0.7978845608f * (yv + 0.044715f * yv * yv * yv)));
    og[j] = f2bf(g);
  }
  uint4 py, pg;
  py.x = oy[0] | ((unsigned)oy[1] << 16); py.y = oy[2] | ((unsigned)oy[3] << 16);
  py.z = oy[4] | ((unsigned)oy[5] << 16); py.w = oy[6] | ((unsigned)oy[7] << 16);
  pg.x = og[0] | ((unsigned)og[1] << 16); pg.y = og[2] | ((unsigned)og[3] << 16);
  pg.z = og[4] | ((unsigned)og[5] << 16); pg.w = og[6] | ((unsigned)og[7] << 16);
  *((uint4*)(y  + (size_t)row * HH) + lane) = py;
  *((uint4*)(x1 + (size_t)row * HH) + lane) = pg;
}

// ---------------- bf16 MFMA GEMM: C[m,n] = sum_k A[m,k] * Wt[n,k] ----------------
// Double-buffered prefetch (T3 minimum 2-phase): stage kt+1 BEFORE computing kt; one
// barrier per step (its vmcnt(0) drain lands after compute covered the load latency).
// T1: XCD-grouped block swizzle. T2: both-sides XOR swizzle (linear gload_lds dest,
// inverse-swizzled global source, swizzled fragment read).
// EPI 0: Cout=bf16 raw. EPI 1: Cout=bf16 acc+Dvec[col]*bf(aux16). EPI 2: f32
//        Cout = skip + bf(aux16)*sigmoid(acc+Dvec[col]).
template <int EPI>
__global__ __launch_bounds__(256, 2) void gemm_kernel(
    const unsigned short* __restrict__ A, const unsigned short* __restrict__ Wt,
    void* __restrict__ Cout, const float* __restrict__ Dvec,
    const unsigned short* __restrict__ aux16, const float* __restrict__ skip) {
  __shared__ alignas(16) unsigned short lA[2][128 * 64];
  __shared__ alignas(16) unsigned short lB[2][128 * 64];
  int tid = threadIdx.x;
  int w = tid >> 6, lane = tid & 63;
  // 1024 blocks; xcd = wgid&7; XCD k owns m-panels [k*32,(k+1)*32)
  int wgid = blockIdx.x;
  int xcd = wgid & 7, bidx = wgid >> 3;         // bidx 0..127
  int m0 = (xcd * 32 + (bidx >> 2)) * 128;      // m-panel
  int n0 = (bidx & 3) * 128;                    // 4 n-blocks adjacent, same XCD
  int wr = w >> 1, wc = w & 1;
  f32x4 acc[4][4];
#pragma unroll
  for (int i = 0; i < 4; i++)
#pragma unroll
    for (int j = 0; j < 4; j++) acc[i][j] = (f32x4){0.f, 0.f, 0.f, 0.f};

  auto stage = [&](int buf, int kt) {
#pragma unroll
    for (int i = 0; i < 4; i++) {  // A tile: 128 rows x 64 cols bf16
      int sidx = i * 256 + tid;
      int r = sidx >> 3, c = sidx & 7;
      int cs = c ^ (r & 7);                     // inverse-swizzled source chunk
      const unsigned short* g = A + (size_t)(m0 + r) * KK + kt * 64 + cs * 8;
      unsigned short* l = &lA[buf][(i * 256 + w * 64) * 8];  // wave-uniform base
      __builtin_amdgcn_global_load_lds((const __attribute__((address_space(1))) void*)g,
                                       (__attribute__((address_space(3))) void*)l, 16, 0, 0);
    }
#pragma unroll
    for (int i = 0; i < 4; i++) {  // Wt tile
      int sidx = i * 256 + tid;
      int r = sidx >> 3, c = sidx & 7;
      int cs = c ^ (r & 7);
      const unsigned short* g = Wt + (size_t)(n0 + r) * KK + kt * 64 + cs * 8;
      unsigned short* l = &lB[buf][(i * 256 + w * 64) * 8];
      __builtin_amdgcn_global_load_lds((const __attribute__((address_space(1))) void*)g,
                                       (__attribute__((address_space(3))) void*)l, 16, 0, 0);
    }
  };

  stage(0, 0);
  __syncthreads();                               // drain prologue loads
#pragma unroll
  for (int kt = 0; kt < NKT; ++kt) {
    int cur = kt & 1;
    if (kt + 1 < NKT) stage(cur ^ 1, kt + 1);    // prefetch next tile (in flight over compute)
#pragma unroll
    for (int ks = 0; ks < 2; ++ks) {
      bf16x8 aF[4], bF[4];
#pragma unroll
      for (int m = 0; m < 4; m++) {
        int row = wr * 64 + m * 16 + (lane & 15);
        int s = ks * 4 + (lane >> 4);
        aF[m] = *reinterpret_cast<const bf16x8*>(&lA[cur][row * 64 + (s ^ (row & 7)) * 8]);
      }
#pragma unroll
      for (int n = 0; n < 4; n++) {
        int row = wc * 64 + n * 16 + (lane & 15);
        int s = ks * 4 + (lane >> 4);
        bF[n] = *reinterpret_cast<const bf16x8*>(&lB[cur][row * 64 + (s ^ (row & 7)) * 8]);
      }
#pragma unroll
      for (int m = 0; m < 4; m++)
#pragma unroll
        for (int n = 0; n < 4; n++)
          acc[m][n] = __builtin_amdgcn_mfma_f32_16x16x32_bf16(aF[m], bF[n], acc[m][n], 0, 0, 0);
    }
    __syncthreads();                             // drains prefetch vmcnt + guards LDS reuse
  }
  // epilogue: C/D layout col=lane&15, row=(lane>>4)*4+j  [m89-verified]
  int lr4 = (lane >> 4) * 4, lc = lane & 15;
#pragma unroll
  for (int m = 0; m < 4; m++) {
    int rowb = m0 + wr * 64 + m * 16 + lr4;
#pragma unroll
    for (int n = 0; n < 4; n++) {
      int col = n0 + wc * 64 + n * 16 + lc;
#pragma unroll
      for (int j = 0; j < 4; j++) {
        int row = rowb + j;
        size_t idxo = (size_t)row * NN + col;
        float v = acc[m][n][j];
        if (EPI == 0) {
          ((unsigned short*)Cout)[idxo] = f2bf(v);
        } else if (EPI == 1) {
          ((unsigned short*)Cout)[idxo] = f2bf(v + Dvec[col] * bf2f(aux16[idxo]));
        } else {
          float z = v + Dvec[col];
          float sg = 1.f / (1.f + expf(-z));
          ((float*)Cout)[idxo] = skip[idxo] + bf2f(aux16[idxo]) * sg;
        }
      }
    }
  }
}

// ---------------- chunked scan (Bu is bf16 now) ----------------
__global__ void scanA_kernel(const unsigned short* __restrict__ Bu, const void* __restrict__ d,
                             const int* __restrict__ dflag, const float* __restrict__ lam_re,
                             const float* __restrict__ lam_im, float* __restrict__ Ar,
                             float* __restrict__ Ai, float* __restrict__ Sr,
                             float* __restrict__ Si) {
  int bx = blockIdx.x;  // c*16 + b
  int c = bx >> 4, b = bx & 15;
  int p = threadIdx.x;
  int fl = *dflag;
  float lr = lam_re[p], li = lam_im[p];
  float Apr = 1.f, Api = 0.f, sr = 0.f, si = 0.f;
  int l0 = c * CLEN;
  for (int j = 0; j < CLEN; j++) {
    int l = l0 + j;
    float kp = keep_val(d, fl, l * BB + b);
    float ar = lr * kp, ai = li * kp;
    size_t ro = (size_t)(l * BB + b) * NN;
    float bur = bf2f(Bu[ro + p]), bui = bf2f(Bu[ro + PP + p]);
    float nsr = ar * sr - ai * si + bur;
    float nsi = ar * si + ai * sr + bui;
    sr = nsr; si = nsi;
    float nar = ar * Apr - ai * Api;
    float nai = ar * Api + ai * Apr;
    Apr = nar; Api = nai;
  }
  int o = bx * PP + p;
  Ar[o] = Apr; Ai[o] = Api; Sr[o] = sr; Si[o] = si;
}

__global__ void scanB_kernel(const float* __restrict__ hr0, const float* __restrict__ hi0,
                             const float* __restrict__ Ar, const float* __restrict__ Ai,
                             const float* __restrict__ Sr, const float* __restrict__ Si,
                             float* __restrict__ Cr, float* __restrict__ Ci,
                             float* __restrict__ outHid) {
  int b = blockIdx.x;
  int p = threadIdx.x;
  float cr = hr0[b * PP + p], ci = hi0[b * PP + p];
  for (int c = 0; c < NC; c++) {
    int o = (c * BB + b) * PP + p;
    Cr[o] = cr; Ci[o] = ci;
    float ar = Ar[o], ai = Ai[o];
    float nr = ar * cr - ai * ci + Sr[o];
    float ni = ar * ci + ai * cr + Si[o];
    cr = nr; ci = ni;
  }
  outHid[b * PP + p] = cr;                 // new_hidden.real
  outHid[BB * PP + b * PP + p] = ci;       // new_hidden.imag
}

__global__ void scanC_kernel(const unsigned short* __restrict__ Bu, const void* __restrict__ d,
                             const int* __restrict__ dflag, const float* __restrict__ lam_re,
                             const float* __restrict__ lam_im, const float* __restrict__ Cr,
                             const float* __restrict__ Ci, unsigned short* __restrict__ xs) {
  int bx = blockIdx.x;
  int c = bx >> 4, b = bx & 15;
  int p = threadIdx.x;
  int fl = *dflag;
  float lr = lam_re[p], li = lam_im[p];
  float hr = Cr[bx * PP + p], hi = Ci[bx * PP + p];
  int l0 = c * CLEN;
  for (int j = 0; j < CLEN; j++) {
    int l = l0 + j;
    float kp = keep_val(d, fl, l * BB + b);
    float ar = lr * kp, ai = li * kp;
    size_t ro = (size_t)(l * BB + b) * NN;
    float bur = bf2f(Bu[ro + p]), bui = bf2f(Bu[ro + PP + p]);
    float nhr = ar * hr - ai * hi + bur;
    float nhi = ar * hi + ai * hr + bui;
    hr = nhr; hi = nhi;
    xs[ro + p] = f2bf(hr);
    xs[ro + PP + p] = f2bf(hi);
  }
}

// ---------------- launcher ----------------
extern "C" void kernel_launch(void* const* d_in, const int* in_sizes, int n_in,
                              void* d_out, int out_size, void* d_ws, size_t ws_size,
                              hipStream_t stream) {
  const float* x    = (const float*)d_in[0];
  const void*  dmask= d_in[1];
  const float* hidr = (const float*)d_in[2];
  const float* hidi = (const float*)d_in[3];
  const float* Lre  = (const float*)d_in[4];
  const float* Lim  = (const float*)d_in[5];
  const float* Bre  = (const float*)d_in[6];
  const float* Bim  = (const float*)d_in[7];
  const float* Cre  = (const float*)d_in[8];
  const float* Cim  = (const float*)d_in[9];
  const float* Dv   = (const float*)d_in[10];
  const float* lst  = (const float*)d_in[11];
  const float* lsc  = (const float*)d_in[12];
  const float* lbs  = (const float*)d_in[13];
  const float* w2   = (const float*)d_in[14];
  const float* b2   = (const float*)d_in[15];
  float* out = (float*)d_out;

  char* ws = (char*)d_ws;
  size_t off = 0;
  auto alloc = [&](size_t bytes) -> void* {
    void* p = ws + off;
    off += (bytes + 255) & ~(size_t)255;
    return p;
  };
  unsigned short* xn  = (unsigned short*)alloc((size_t)MM * KK * 2);  // 32MB; reused as y
  unsigned short* xs  = (unsigned short*)alloc((size_t)MM * KK * 2);  // 32MB; reused as x1
  unsigned short* Bu  = (unsigned short*)alloc((size_t)MM * NN * 2);  // 32MB bf16; reused as ys
  unsigned short* W1t = (unsigned short*)alloc((size_t)NN * KK * 2);
  unsigned short* W2t = (unsigned short*)alloc((size_t)NN * KK * 2);
  unsigned short* W3t = (unsigned short*)alloc((size_t)NN * KK * 2);
  float* lam_re = (float*)alloc(PP * 4);
  float* lam_im = (float*)alloc(PP * 4);
  float* Ar = (float*)alloc((size_t)NC * BB * PP * 4);
  float* Ai = (float*)alloc((size_t)NC * BB * PP * 4);
  float* Sr = (float*)alloc((size_t)NC * BB * PP * 4);
  float* Si = (float*)alloc((size_t)NC * BB * PP * 4);
  float* Cr = (float*)alloc((size_t)NC * BB * PP * 4);
  float* Ci = (float*)alloc((size_t)NC * BB * PP * 4);
  int* dflag = (int*)alloc(256);
  unsigned short* y   = xn;   // reuse after GEMM2 consumed xn
  unsigned short* x1  = xs;   // reuse after GEMM2 consumed xs
  unsigned short* ysb = Bu;   // reuse after scan consumed Bu

  detect_kernel<<<1, 256, 0, stream>>>((const unsigned int*)dmask, dflag);
  precompute_kernel<<<1024, 256, 0, stream>>>(Lre, Lim, Bre, Bim, Cre, Cim, lst, w2,
                                              W1t, W2t, W3t, lam_re, lam_im);
  ln1_kernel<<<MM / 4, 256, 0, stream>>>(x, lsc, lbs, xn);
  gemm_kernel<0><<<1024, 256, 0, stream>>>(xn, W1t, Bu, nullptr, nullptr, nullptr);
  scanA_kernel<<<NC * BB, 256, 0, stream>>>(Bu, dmask, dflag, lam_re, lam_im, Ar, Ai, Sr, Si);
  scanB_kernel<<<BB, 256, 0, stream>>>(hidr, hidi, Ar, Ai, Sr, Si, Cr, Ci, out);
  scanC_kernel<<<NC * BB, 256, 0, stream>>>(Bu, dmask, dflag, lam_re, lam_im, Cr, Ci, xs);
  gemm_kernel<1><<<1024, 256, 0, stream>>>(xs, W2t, ysb, Dv, xn, nullptr);
  ln2_kernel<<<MM / 4, 256, 0, stream>>>(ysb, lsc, lbs, y, x1);
  gemm_kernel<2><<<1024, 256, 0, stream>>>(x1, W3t, out + 2 * BB * PP, b2, y, x);
}